// Round 1
// baseline (246.842 us; speedup 1.0000x reference)
//
#include <hip/hip_runtime.h>
#include <math.h>

#define SEQ    4096
#define DMODEL 1024
#define NHEADS 16
#define DK     64

typedef unsigned short u16;
typedef short bh8 __attribute__((ext_vector_type(8)));   // 8 x bf16 (4 VGPRs)
typedef float f4  __attribute__((ext_vector_type(4)));   // 4 x fp32 acc

__device__ __forceinline__ u16 f2b(float f) {            // RNE
    union { float f; unsigned u; } v; v.f = f;
    unsigned u = v.u;
    return (u16)((u + 0x7FFFu + ((u >> 16) & 1u)) >> 16);
}
__device__ __forceinline__ unsigned pk2(float a, float b) {  // trunc pack 2xbf16
    union { float f; unsigned u; } ua, ub; ua.f = a; ub.f = b;
    return (ua.u >> 16) | (ub.u & 0xFFFF0000u);
}

// ---------------------------------------------------------------------------
// Merged fp32 -> bf16 convert for x and all 4 weights (one launch).
// ---------------------------------------------------------------------------
__global__ void cvt_all_kernel(const float* __restrict__ x,
                               const float* __restrict__ wq, const float* __restrict__ wk,
                               const float* __restrict__ wv, const float* __restrict__ wo,
                               u16* __restrict__ xb, u16* __restrict__ wb)
{
    const int NX = SEQ * DMODEL / 8;        // 524288 chunks of 8
    const int NW = DMODEL * DMODEL / 8;     // 131072
    int i = blockIdx.x * blockDim.x + threadIdx.x;
    if (i >= NX + 4 * NW) return;
    const float* src; u16* dst; int j;
    if (i < NX) { src = x; dst = xb; j = i; }
    else {
        int k = i - NX;
        int wsel = k >> 17;                 // NW = 2^17
        j = k & (NW - 1);
        src = (wsel == 0) ? wq : (wsel == 1) ? wk : (wsel == 2) ? wv : wo;
        dst = wb + (size_t)wsel * DMODEL * DMODEL;
    }
    const float4* p = (const float4*)src + (size_t)j * 2;
    float4 a = p[0], b = p[1];
    __align__(16) u16 r[8] = { f2b(a.x), f2b(a.y), f2b(a.z), f2b(a.w),
                               f2b(b.x), f2b(b.y), f2b(b.z), f2b(b.w) };
    *(uint4*)(dst + (size_t)j * 8) = *(const uint4*)r;
}

// ---------------------------------------------------------------------------
// bf16 MFMA GEMM (bt-form), BK=32, 4 waves.
// MODE 0: 128x64 tile, fp32 out.  MODE 2: 128x128, fused QKV epilogue
// (Q: RoPE * 0.125*log2e pre-scale -> [h][s][64]; K: RoPE -> [h][s][64];
//  V: transposed -> [h][64][s]).
// ---------------------------------------------------------------------------
template<int MODE>
__global__ __launch_bounds__(256) void gemm_bt(
    const u16* __restrict__ A, const u16* __restrict__ B,
    void* __restrict__ out, u16* __restrict__ Qh, u16* __restrict__ Kh,
    u16* __restrict__ Vt, int M, int N, int K)
{
    constexpr int BN = (MODE == 0) ? 64 : 128;
    constexpr int NJ = BN / 32;             // j-tiles per wave (2 or 4)

    __shared__ __align__(16) u16 As[128 * 32];
    __shared__ __align__(16) u16 Bs[BN * 32];

    const int t    = threadIdx.x;
    const int w    = t >> 6, lane = t & 63;
    const int quad = lane >> 4, l16 = lane & 15;
    const int wm   = w >> 1,  wn  = w & 1;
    const int m0   = blockIdx.y * 128, n0 = blockIdx.x * BN;
    const int lr   = lane >> 2;             // 0..15
    const int lc   = (lane & 3) * 8;        // 0,8,16,24

    f4 acc[4][NJ];
#pragma unroll
    for (int i = 0; i < 4; ++i)
#pragma unroll
        for (int j = 0; j < NJ; ++j) { f4 z = {0.f,0.f,0.f,0.f}; acc[i][j] = z; }

    const int c0 = 2 * w, c1 = 2 * w + 1;

    for (int k0 = 0; k0 < K; k0 += 32) {
        __builtin_amdgcn_global_load_lds(
            (const __attribute__((address_space(1))) unsigned int*)(A + (size_t)(m0 + c0*16 + lr)*K + k0 + lc),
            (__attribute__((address_space(3))) unsigned int*)(As + c0*512), 16, 0, 0);
        __builtin_amdgcn_global_load_lds(
            (const __attribute__((address_space(1))) unsigned int*)(A + (size_t)(m0 + c1*16 + lr)*K + k0 + lc),
            (__attribute__((address_space(3))) unsigned int*)(As + c1*512), 16, 0, 0);
        if (MODE == 0) {
            __builtin_amdgcn_global_load_lds(
                (const __attribute__((address_space(1))) unsigned int*)(B + (size_t)(n0 + w*16 + lr)*K + k0 + lc),
                (__attribute__((address_space(3))) unsigned int*)(Bs + w*512), 16, 0, 0);
        } else {
            __builtin_amdgcn_global_load_lds(
                (const __attribute__((address_space(1))) unsigned int*)(B + (size_t)(n0 + c0*16 + lr)*K + k0 + lc),
                (__attribute__((address_space(3))) unsigned int*)(Bs + c0*512), 16, 0, 0);
            __builtin_amdgcn_global_load_lds(
                (const __attribute__((address_space(1))) unsigned int*)(B + (size_t)(n0 + c1*16 + lr)*K + k0 + lc),
                (__attribute__((address_space(3))) unsigned int*)(Bs + c1*512), 16, 0, 0);
        }
        __syncthreads();

        bh8 af[4], bf_[NJ];
#pragma unroll
        for (int i = 0; i < 4; ++i)
            af[i] = *(const bh8*)&As[(wm*64 + i*16 + l16)*32 + quad*8];
#pragma unroll
        for (int j = 0; j < NJ; ++j)
            bf_[j] = *(const bh8*)&Bs[(wn*(BN/2) + j*16 + l16)*32 + quad*8];
#pragma unroll
        for (int i = 0; i < 4; ++i)
#pragma unroll
            for (int j = 0; j < NJ; ++j)
                acc[i][j] = __builtin_amdgcn_mfma_f32_16x16x32_bf16(af[i], bf_[j], acc[i][j], 0, 0, 0);
        __syncthreads();
    }

    if (MODE == 0) {
#pragma unroll
        for (int i = 0; i < 4; ++i) {
            const int row = m0 + wm*64 + i*16 + quad*4;
#pragma unroll
            for (int j = 0; j < NJ; ++j) {
                const int col = n0 + wn*(BN/2) + j*16 + l16;
#pragma unroll
                for (int r = 0; r < 4; ++r)
                    ((float*)out)[(size_t)(row + r) * N + col] = acc[i][j][r];
            }
        }
    } else {
        const int sect  = n0 >> 10;                   // 0=Q,1=K,2=V (block-uniform)
        const int cbase = (n0 & 1023) + wn * 64;      // 64-aligned head base
        const int hh    = cbase >> 6;                 // head (wave-uniform)
        if (sect < 2) {
            u16* dst = (sect == 0) ? Qh : Kh;
            const float qscl = (sect == 0) ? 0.18033688011112042f : 1.0f; // 0.125*log2(e)
#pragma unroll
            for (int j = 0; j < NJ; ++j) {
                const int d = j * 16 + l16;           // 0..63 within head
                const float invf2 = exp2f((float)(d & ~1) * (-13.287712379549449f / 64.0f))
                                    * 0.15915494309189535f;
#pragma unroll
                for (int i = 0; i < 4; ++i) {
                    const int srow0 = m0 + wm*64 + i*16 + quad*4;
#pragma unroll
                    for (int r = 0; r < 4; ++r) {
                        float own = acc[i][j][r];
                        float oth = __shfl_xor(own, 1);      // rope pair partner
                        float rev = (float)(srow0 + r) * invf2;
                        rev -= floorf(rev);                   // v_sin input: revolutions
                        float sn = __builtin_amdgcn_sinf(rev);
                        float cs = __builtin_amdgcn_cosf(rev);
                        float xe = (l16 & 1) ? oth : own;
                        float xo = (l16 & 1) ? own : oth;
                        float val = (l16 & 1) ? (sn * xe + cs * xo)
                                              : (cs * xe - sn * xo);
                        dst[((size_t)hh * SEQ + srow0 + r) * DK + d] = f2b(val * qscl);
                    }
                }
            }
        } else {
#pragma unroll
            for (int j = 0; j < NJ; ++j) {
                const int d = j * 16 + l16;
#pragma unroll
                for (int i = 0; i < 4; ++i) {
                    const int srow0 = m0 + wm*64 + i*16 + quad*4;
                    __align__(8) u16 pk[4];
#pragma unroll
                    for (int r = 0; r < 4; ++r) pk[r] = f2b(acc[i][j][r]);
                    *(unsigned long long*)&Vt[((size_t)hh * DK + d) * SEQ + srow0] =
                        *(const unsigned long long*)pk;
                }
            }
        }
    }
}

// ---------------------------------------------------------------------------
// MFMA flash attention, register-resident P.
// This revision attacks the LDS pipe (the measured bottleneck):
//  * staging via global_load_lds (no ds_write_b128 -> kills the 12.8M
//    bank-conflict cycles that exactly matched 4-way-conflicted uint4 writes)
//  * LDS tiles are linear [64][64] u16; bank swizzle (slot16 ^= row&7) is
//    baked into the per-lane GLOBAL source address (m173 pattern), reads
//    apply the same XOR -> conflict-free b128 fragment reads
//  * V staged with a key permutation key' = kbp*32+quad*8+half*4+t (4B-
//    granular global_load_lds) so PV runs as 8x mfma_16x16x32 with single
//    b128 V fragments instead of 16x mfma_16x16x16 + 16x ds_read_b64
// Scores stay transposed (S^T = K*Q^T); softmax via exp2 (Q pre-scaled);
// grid = R9 serpentine (48,16); 1 barrier/step (implicit vmcnt(0) at the
// barrier is the prefetch-distance-1 wait for the global_load_lds issued
// at the top of the step).
// ---------------------------------------------------------------------------
__global__ __launch_bounds__(256) void attn_mfma_kernel(
    const u16* __restrict__ Qh, const u16* __restrict__ Kh,
    const u16* __restrict__ Vt, u16* __restrict__ ctx)
{
    __shared__ __align__(16) u16 Ks[2][64 * 64];   // [key][d]   (swizzled slots)
    __shared__ __align__(16) u16 Vs[2][64 * 64];   // [d][key']  (permuted+swizzled)

    const int h    = blockIdx.y;
    const int b48  = blockIdx.x;                   // 0..47
    const int t    = threadIdx.x;
    const int w    = t >> 6, lane = t & 63;
    const int quad = lane >> 4, l16 = lane & 15;

    const u16* Kbase = Kh + (size_t)h * SEQ * DK;
    const u16* Vbase = Vt + (size_t)h * DK * SEQ;

    // lane-constant swizzled fragment column offsets (u16 units):
    // logical 16B slot L at row r lives at physical slot L ^ (r&7); for all
    // fragment reads the row's low 3 bits are l16&7.
    const int sA = ((quad       ^ (l16 & 7)) * 8);   // slots 0..3  (dims 0..31 / kbp=0)
    const int sB = (((4 + quad) ^ (l16 & 7)) * 8);   // slots 4..7  (dims 32..63 / kbp=1)

    // K staging: 2 instrs x 16B/lane. LDS 16B-slot = w*128 + i*64 + lane,
    // row r = slot>>3, s = slot&7; source column = (s ^ (r&7))*8.
    int koff[2];
    {
        const int r7 = lane >> 3;                    // row low bits (= r&7)
        const int s  = lane & 7;
#pragma unroll
        for (int i = 0; i < 2; ++i) {
            const int r = w * 16 + i * 8 + r7;
            koff[i] = r * DK + ((s ^ r7) * 8);
        }
    }
    // V staging: 8 instrs x 4B/lane. LDS 4B-slot = w*512 + i*64 + lane,
    // row d = slot>>5, piece p = lane&31 (c = p>>2 16B slot, sub = p&3).
    // logical slot cl = c ^ (d&7); its keys' kappa = cl*8 + sub*2 map back to
    // original keys key0 = (cl>>2)*32 + (sub>>1)*16 + (cl&3)*4 + (sub&1)*2.
    int voff[8];
    {
        const int ln5 = lane >> 5;
        const int c   = (lane & 31) >> 2;
        const int sub = lane & 3;
#pragma unroll
        for (int i = 0; i < 8; ++i) {
            const int d   = w * 16 + i * 2 + ln5;
            const int cl  = c ^ (d & 7);
            const int ky0 = (cl >> 2) * 32 + (sub >> 1) * 16 + (cl & 3) * 4 + (sub & 1) * 2;
            voff[i] = d * SEQ + ky0;
        }
    }

    const int np = (b48 >= 32) ? 2 : 1;

    for (int part = 0; part < np; ++part) {
        const int qt = (part == 0) ? (63 - b48) : (b48 - 32);
        const int q0 = qt * 64;
        const int nk = qt + 1;

        // Q fragment (B-operand: B[n=l16][k=quad*8+j])
        bh8 qa0, qa1;
        {
            const u16* qrow = Qh + ((size_t)h * SEQ + q0 + w * 16 + l16) * DK;
            qa0 = *(const bh8*)(qrow + quad * 8);
            qa1 = *(const bh8*)(qrow + 32 + quad * 8);
        }

        f4 o[4];               // O^T: lane l16 = q-row, row quad*4+r = dim (per 16-dim block jd)
        float lsum = 0.f;      // per-lane partial row sum (q-row l16)
#pragma unroll
        for (int j = 0; j < 4; ++j) { f4 z = {0.f,0.f,0.f,0.f}; o[j] = z; }

        // ---- prologue: stage k-tile 0 into buffer 0 (prev part's last
        // barrier already protects the buffers) ----
#pragma unroll
        for (int i = 0; i < 2; ++i)
            __builtin_amdgcn_global_load_lds(
                (const __attribute__((address_space(1))) unsigned int*)(Kbase + koff[i]),
                (__attribute__((address_space(3))) unsigned int*)&Ks[0][(w * 128 + i * 64) * 8],
                16, 0, 0);
#pragma unroll
        for (int i = 0; i < 8; ++i)
            __builtin_amdgcn_global_load_lds(
                (const __attribute__((address_space(1))) unsigned int*)(Vbase + voff[i]),
                (__attribute__((address_space(3))) unsigned int*)&Vs[0][(w * 512 + i * 64) * 2],
                4, 0, 0);
        __syncthreads();       // implicit vmcnt(0): tile 0 resident

        int b = 0;
        for (int kt = 0; kt < nk; ++kt) {
            const bool have_next = (kt + 1 < nk);

            if (have_next) {   // issue next-tile loads early; they complete
                               // under this step's compute, waited at barrier
                const size_t kn = (size_t)(kt + 1) * 64;
#pragma unroll
                for (int i = 0; i < 2; ++i)
                    __builtin_amdgcn_global_load_lds(
                        (const __attribute__((address_space(1))) unsigned int*)(Kbase + kn * DK + koff[i]),
                        (__attribute__((address_space(3))) unsigned int*)&Ks[b ^ 1][(w * 128 + i * 64) * 8],
                        16, 0, 0);
#pragma unroll
                for (int i = 0; i < 8; ++i)
                    __builtin_amdgcn_global_load_lds(
                        (const __attribute__((address_space(1))) unsigned int*)(Vbase + kn + voff[i]),
                        (__attribute__((address_space(3))) unsigned int*)&Vs[b ^ 1][(w * 512 + i * 64) * 2],
                        4, 0, 0);
            }

            // ---- S^T = K*Q^T: per lane, col=q-row l16, row=key quad*4+r ----
            float sv[4][4];
#pragma unroll
            for (int kb = 0; kb < 4; ++kb) {
                const int rb = (kb * 16 + l16) * 64;
                bh8 kf0 = *(const bh8*)&Ks[b][rb + sA];
                bh8 kf1 = *(const bh8*)&Ks[b][rb + sB];
                f4 a = {0.f,0.f,0.f,0.f};
                a = __builtin_amdgcn_mfma_f32_16x16x32_bf16(kf0, qa0, a, 0, 0, 0);  // A=K, B=Q
                a = __builtin_amdgcn_mfma_f32_16x16x32_bf16(kf1, qa1, a, 0, 0, 0);
#pragma unroll
                for (int r = 0; r < 4; ++r) sv[kb][r] = a[r];
            }
            // diagonal masking: key = k0+kb*16+quad*4+r, q-row = q0+w*16+l16
            if (kt == qt) {
#pragma unroll
                for (int kb = 0; kb < 4; ++kb)
#pragma unroll
                    for (int r = 0; r < 4; ++r)
                        if (kb * 16 + quad * 4 + r > w * 16 + l16) sv[kb][r] = -1.0e30f;
            }

            // ---- p = 2^sv (Q pre-scaled) ----
            float p[4][4];
#pragma unroll
            for (int kb = 0; kb < 4; ++kb) {
                p[kb][0] = exp2f(sv[kb][0]); p[kb][1] = exp2f(sv[kb][1]);
                p[kb][2] = exp2f(sv[kb][2]); p[kb][3] = exp2f(sv[kb][3]);
                lsum += (p[kb][0] + p[kb][1]) + (p[kb][2] + p[kb][3]);
            }

            // ---- PV: 8x mfma_16x16x32; pb covers two adjacent 16-key
            // blocks, va is the matching permuted b128 V^T fragment ----
#pragma unroll
            for (int kbp = 0; kbp < 2; ++kbp) {
                union { unsigned u[4]; bh8 v; } pc;
                pc.u[0] = pk2(p[2*kbp][0],     p[2*kbp][1]);
                pc.u[1] = pk2(p[2*kbp][2],     p[2*kbp][3]);
                pc.u[2] = pk2(p[2*kbp + 1][0], p[2*kbp + 1][1]);
                pc.u[3] = pk2(p[2*kbp + 1][2], p[2*kbp + 1][3]);
                const bh8 pb = pc.v;
                const int sc = kbp ? sB : sA;
#pragma unroll
                for (int jd = 0; jd < 4; ++jd) {
                    bh8 va = *(const bh8*)&Vs[b][(jd * 16 + l16) * 64 + sc];
                    o[jd] = __builtin_amdgcn_mfma_f32_16x16x32_bf16(va, pb, o[jd], 0, 0, 0);
                }
            }

            __syncthreads();   // drains vmcnt -> next buffer ready; also
                               // orders this step's LDS reads vs next writes
            if (have_next) b ^= 1;
        }

        // ---- epilogue: reduce l across quads (rows live in l16), store ----
        lsum += __shfl_xor(lsum, 16);
        lsum += __shfl_xor(lsum, 32);
        const float linv = 1.f / lsum;
        const size_t rowbase = (size_t)(q0 + w * 16 + l16) * DMODEL + h * DK;
#pragma unroll
        for (int jd = 0; jd < 4; ++jd) {
            unsigned lo = (unsigned)f2b(o[jd][0] * linv) | ((unsigned)f2b(o[jd][1] * linv) << 16);
            unsigned hi = (unsigned)f2b(o[jd][2] * linv) | ((unsigned)f2b(o[jd][3] * linv) << 16);
            uint2 pkd; pkd.x = lo; pkd.y = hi;
            *(uint2*)&ctx[rowbase + jd * 16 + quad * 4] = pkd;   // O[row][d..d+3]
        }
    }
}

// ---------------------------------------------------------------------------
extern "C" void kernel_launch(void* const* d_in, const int* in_sizes, int n_in,
                              void* d_out, int out_size, void* d_ws, size_t ws_size,
                              hipStream_t stream)
{
    const float* x  = (const float*)d_in[0];
    const float* wq = (const float*)d_in[1];
    const float* wk = (const float*)d_in[2];
    const float* wv = (const float*)d_in[3];
    const float* wo = (const float*)d_in[4];
    float* out = (float*)d_out;

    char* ws = (char*)d_ws;
    const size_t MB = 1u << 20;
    u16* xb   = (u16*)(ws);              // 8 MB  [4096][1024] bf16
    u16* wqkv = (u16*)(ws + 8  * MB);    // 6 MB  [3072][1024] bf16 (wq|wk|wv)
    u16* wob  = (u16*)(ws + 14 * MB);    // 2 MB  (contiguous after wqkv)
    u16* Qh   = (u16*)(ws + 16 * MB);    // 8 MB  [h][s][64]  (pre-scaled by 0.125*log2e)
    u16* Kh   = (u16*)(ws + 24 * MB);    // 8 MB
    u16* Vtb  = (u16*)(ws + 32 * MB);    // 8 MB  [h][64][s]
    u16* ctxb = (u16*)(ws + 40 * MB);    // 8 MB  [s][1024]

    const int NCVT = SEQ * DMODEL / 8 + 4 * (DMODEL * DMODEL / 8);   // 1048576
    cvt_all_kernel<<<NCVT / 256, 256, 0, stream>>>(x, wq, wk, wv, wo, xb, wqkv);

    dim3 gqkv(3 * DMODEL / 128, SEQ / 128);   // (24, 32) = 768 blocks
    gemm_bt<2><<<gqkv, 256, 0, stream>>>(xb, wqkv, nullptr, Qh, Kh, Vtb,
                                         SEQ, 3 * DMODEL, DMODEL);

    attn_mfma_kernel<<<dim3(48, NHEADS), 256, 0, stream>>>(Qh, Kh, Vtb, ctxb);

    dim3 go(DMODEL / 64, SEQ / 128);          // (16, 32) = 512 blocks
    gemm_bt<0><<<go, 256, 0, stream>>>(ctxb, wob, out, nullptr, nullptr, nullptr,
                                       SEQ, DMODEL, DMODEL);
}

// Round 2
// 233.980 us; speedup vs baseline: 1.0550x; 1.0550x over previous
//
#include <hip/hip_runtime.h>
#include <math.h>

#define SEQ    4096
#define DMODEL 1024
#define NHEADS 16
#define DK     64

typedef unsigned short u16;
typedef short bh8 __attribute__((ext_vector_type(8)));   // 8 x bf16 (4 VGPRs)
typedef float f4  __attribute__((ext_vector_type(4)));   // 4 x fp32 acc

__device__ __forceinline__ u16 f2b(float f) {            // RNE
    union { float f; unsigned u; } v; v.f = f;
    unsigned u = v.u;
    return (u16)((u + 0x7FFFu + ((u >> 16) & 1u)) >> 16);
}
__device__ __forceinline__ unsigned pk2(float a, float b) {  // trunc pack 2xbf16
    union { float f; unsigned u; } ua, ub; ua.f = a; ub.f = b;
    return (ua.u >> 16) | (ub.u & 0xFFFF0000u);
}

// ---------------------------------------------------------------------------
// Merged fp32 -> bf16 convert for x and all 4 weights (one launch).
// ---------------------------------------------------------------------------
__global__ void cvt_all_kernel(const float* __restrict__ x,
                               const float* __restrict__ wq, const float* __restrict__ wk,
                               const float* __restrict__ wv, const float* __restrict__ wo,
                               u16* __restrict__ xb, u16* __restrict__ wb)
{
    const int NX = SEQ * DMODEL / 8;        // 524288 chunks of 8
    const int NW = DMODEL * DMODEL / 8;     // 131072
    int i = blockIdx.x * blockDim.x + threadIdx.x;
    if (i >= NX + 4 * NW) return;
    const float* src; u16* dst; int j;
    if (i < NX) { src = x; dst = xb; j = i; }
    else {
        int k = i - NX;
        int wsel = k >> 17;                 // NW = 2^17
        j = k & (NW - 1);
        src = (wsel == 0) ? wq : (wsel == 1) ? wk : (wsel == 2) ? wv : wo;
        dst = wb + (size_t)wsel * DMODEL * DMODEL;
    }
    const float4* p = (const float4*)src + (size_t)j * 2;
    float4 a = p[0], b = p[1];
    __align__(16) u16 r[8] = { f2b(a.x), f2b(a.y), f2b(a.z), f2b(a.w),
                               f2b(b.x), f2b(b.y), f2b(b.z), f2b(b.w) };
    *(uint4*)(dst + (size_t)j * 8) = *(const uint4*)r;
}

// ---------------------------------------------------------------------------
// bf16 MFMA GEMM (bt-form), BK=32, 4 waves.
// MODE 0: 128x64 tile, fp32 out.  MODE 2: 128x128, fused QKV epilogue
// (Q: RoPE * 0.125*log2e pre-scale -> [h][s][64]; K: RoPE -> [h][s][64];
//  V: transposed -> [h][64][s]).
// ---------------------------------------------------------------------------
template<int MODE>
__global__ __launch_bounds__(256) void gemm_bt(
    const u16* __restrict__ A, const u16* __restrict__ B,
    void* __restrict__ out, u16* __restrict__ Qh, u16* __restrict__ Kh,
    u16* __restrict__ Vt, int M, int N, int K)
{
    constexpr int BN = (MODE == 0) ? 64 : 128;
    constexpr int NJ = BN / 32;             // j-tiles per wave (2 or 4)

    __shared__ __align__(16) u16 As[128 * 32];
    __shared__ __align__(16) u16 Bs[BN * 32];

    const int t    = threadIdx.x;
    const int w    = t >> 6, lane = t & 63;
    const int quad = lane >> 4, l16 = lane & 15;
    const int wm   = w >> 1,  wn  = w & 1;
    const int m0   = blockIdx.y * 128, n0 = blockIdx.x * BN;
    const int lr   = lane >> 2;             // 0..15
    const int lc   = (lane & 3) * 8;        // 0,8,16,24

    f4 acc[4][NJ];
#pragma unroll
    for (int i = 0; i < 4; ++i)
#pragma unroll
        for (int j = 0; j < NJ; ++j) { f4 z = {0.f,0.f,0.f,0.f}; acc[i][j] = z; }

    const int c0 = 2 * w, c1 = 2 * w + 1;

    for (int k0 = 0; k0 < K; k0 += 32) {
        __builtin_amdgcn_global_load_lds(
            (const __attribute__((address_space(1))) unsigned int*)(A + (size_t)(m0 + c0*16 + lr)*K + k0 + lc),
            (__attribute__((address_space(3))) unsigned int*)(As + c0*512), 16, 0, 0);
        __builtin_amdgcn_global_load_lds(
            (const __attribute__((address_space(1))) unsigned int*)(A + (size_t)(m0 + c1*16 + lr)*K + k0 + lc),
            (__attribute__((address_space(3))) unsigned int*)(As + c1*512), 16, 0, 0);
        if (MODE == 0) {
            __builtin_amdgcn_global_load_lds(
                (const __attribute__((address_space(1))) unsigned int*)(B + (size_t)(n0 + w*16 + lr)*K + k0 + lc),
                (__attribute__((address_space(3))) unsigned int*)(Bs + w*512), 16, 0, 0);
        } else {
            __builtin_amdgcn_global_load_lds(
                (const __attribute__((address_space(1))) unsigned int*)(B + (size_t)(n0 + c0*16 + lr)*K + k0 + lc),
                (__attribute__((address_space(3))) unsigned int*)(Bs + c0*512), 16, 0, 0);
            __builtin_amdgcn_global_load_lds(
                (const __attribute__((address_space(1))) unsigned int*)(B + (size_t)(n0 + c1*16 + lr)*K + k0 + lc),
                (__attribute__((address_space(3))) unsigned int*)(Bs + c1*512), 16, 0, 0);
        }
        __syncthreads();

        bh8 af[4], bf_[NJ];
#pragma unroll
        for (int i = 0; i < 4; ++i)
            af[i] = *(const bh8*)&As[(wm*64 + i*16 + l16)*32 + quad*8];
#pragma unroll
        for (int j = 0; j < NJ; ++j)
            bf_[j] = *(const bh8*)&Bs[(wn*(BN/2) + j*16 + l16)*32 + quad*8];
#pragma unroll
        for (int i = 0; i < 4; ++i)
#pragma unroll
            for (int j = 0; j < NJ; ++j)
                acc[i][j] = __builtin_amdgcn_mfma_f32_16x16x32_bf16(af[i], bf_[j], acc[i][j], 0, 0, 0);
        __syncthreads();
    }

    if (MODE == 0) {
#pragma unroll
        for (int i = 0; i < 4; ++i) {
            const int row = m0 + wm*64 + i*16 + quad*4;
#pragma unroll
            for (int j = 0; j < NJ; ++j) {
                const int col = n0 + wn*(BN/2) + j*16 + l16;
#pragma unroll
                for (int r = 0; r < 4; ++r)
                    ((float*)out)[(size_t)(row + r) * N + col] = acc[i][j][r];
            }
        }
    } else {
        const int sect  = n0 >> 10;                   // 0=Q,1=K,2=V (block-uniform)
        const int cbase = (n0 & 1023) + wn * 64;      // 64-aligned head base
        const int hh    = cbase >> 6;                 // head (wave-uniform)
        if (sect < 2) {
            u16* dst = (sect == 0) ? Qh : Kh;
            const float qscl = (sect == 0) ? 0.18033688011112042f : 1.0f; // 0.125*log2(e)
#pragma unroll
            for (int j = 0; j < NJ; ++j) {
                const int d = j * 16 + l16;           // 0..63 within head
                const float invf2 = exp2f((float)(d & ~1) * (-13.287712379549449f / 64.0f))
                                    * 0.15915494309189535f;
#pragma unroll
                for (int i = 0; i < 4; ++i) {
                    const int srow0 = m0 + wm*64 + i*16 + quad*4;
#pragma unroll
                    for (int r = 0; r < 4; ++r) {
                        float own = acc[i][j][r];
                        float oth = __shfl_xor(own, 1);      // rope pair partner
                        float rev = (float)(srow0 + r) * invf2;
                        rev -= floorf(rev);                   // v_sin input: revolutions
                        float sn = __builtin_amdgcn_sinf(rev);
                        float cs = __builtin_amdgcn_cosf(rev);
                        float xe = (l16 & 1) ? oth : own;
                        float xo = (l16 & 1) ? own : oth;
                        float val = (l16 & 1) ? (sn * xe + cs * xo)
                                              : (cs * xe - sn * xo);
                        dst[((size_t)hh * SEQ + srow0 + r) * DK + d] = f2b(val * qscl);
                    }
                }
            }
        } else {
#pragma unroll
            for (int j = 0; j < NJ; ++j) {
                const int d = j * 16 + l16;
#pragma unroll
                for (int i = 0; i < 4; ++i) {
                    const int srow0 = m0 + wm*64 + i*16 + quad*4;
                    __align__(8) u16 pk[4];
#pragma unroll
                    for (int r = 0; r < 4; ++r) pk[r] = f2b(acc[i][j][r]);
                    *(unsigned long long*)&Vt[((size_t)hh * DK + d) * SEQ + srow0] =
                        *(const unsigned long long*)pk;
                }
            }
        }
    }
}

// ---------------------------------------------------------------------------
// MFMA flash attention, register-resident P.
// R2: hybrid staging (best of R0's schedule + R1's conflict-free layout).
//  * K: global_load_lds 16B/lane, linear dest, swizzle baked into the global
//    source column (R1's koff) — issued at step TOP into buf^1, drained by
//    the bottom barrier (full-step latency hiding).
//  * V: R0-style coalesced uint4 register loads at step TOP; permuted +
//    XOR-swizzled ds_write_b64 pairs AFTER PV (write addrs are per-thread
//    constants; bank-exact: each 16-lane write phase touches 32 distinct
//    banks). This removes R1's scattered 4B global_load_lds (the +12us
//    regression) while keeping SQ_LDS_BANK_CONFLICT at 0.
//  * PV stays 8x mfma_16x16x32 with single b128 V fragments (key perm
//    key = kbp*32 + jhi*16 + quad*4 + jlow <-> kappa = kbp*32+quad*8+j).
//  * T5: s_setprio(1) around both MFMA clusters (3 indep blocks/CU).
// Scores transposed (S^T = K*Q^T); softmax exp2, Q pre-scaled; serpentine
// grid (48,16); one barrier per steady-state step.
// ---------------------------------------------------------------------------
__global__ __launch_bounds__(256) void attn_mfma_kernel(
    const u16* __restrict__ Qh, const u16* __restrict__ Kh,
    const u16* __restrict__ Vt, u16* __restrict__ ctx)
{
    __shared__ __align__(16) u16 Ks[2][64 * 64];   // [key][d]   (swizzled slots)
    __shared__ __align__(16) u16 Vs[2][64 * 64];   // [d][key']  (permuted+swizzled)

    const int h    = blockIdx.y;
    const int b48  = blockIdx.x;                   // 0..47
    const int t    = threadIdx.x;
    const int w    = t >> 6, lane = t & 63;
    const int quad = lane >> 4, l16 = lane & 15;

    const u16* Kbase = Kh + (size_t)h * SEQ * DK;
    const u16* Vbase = Vt + (size_t)h * DK * SEQ;

    // fragment-read swizzled column offsets (u16 units): logical 16B slot L
    // at row r lives at physical slot L ^ (r&7); fragment rows have low3 = l16&7.
    const int sA = ((quad       ^ (l16 & 7)) * 8);   // slots 0..3
    const int sB = (((4 + quad) ^ (l16 & 7)) * 8);   // slots 4..7

    // K staging (global_load_lds): 2 x 16B/lane. Dest 16B-slot = w*128+i*64+lane
    // (linear); row r = slot>>3, s = slot&7; source col = (s ^ (r&7))*8.
    int koff[2];
    {
        const int r7 = lane >> 3;
        const int s  = lane & 7;
#pragma unroll
        for (int i = 0; i < 2; ++i) {
            const int r = w * 16 + i * 8 + r7;
            koff[i] = r * DK + ((s ^ r7) * 8);
        }
    }

    // V staging (reg + ds_write): thread t owns row d = t>>2, source cols
    // c2 = (t&3)*2 + i (16B each). The uint4 (keys c2*8..c2*8+7) splits into
    // two 4-key chunks written at permuted kappas:
    //   kappa(key): kbp=key>>5, jhi=(key>>4)&1, q=(key>>2)&3, jl=key&3
    //               -> kbp*32 + q*8 + jhi*4 + jl
    // chunk bases: qa=(2*(c2&3))&3 (keys r=0..3), qb=qa+1 (keys r=4..7).
    // Byte addr swizzle: slot = kappa>>3 -> slot ^ (d&7).
    const int vd  = t >> 2;                 // 0..63
    const int vs0 = (t & 3) * 16;           // source col (u16), +8 for i=1
    int wv[2][2];
    {
        const int vd7 = vd & 7;
#pragma unroll
        for (int i = 0; i < 2; ++i) {
            const int c2  = (t & 3) * 2 + i;
            const int kbp = c2 >> 2, cm = c2 & 3;
            const int qa  = (2 * cm) & 3;
            const int qb  = (2 * cm + 1) & 3;
            const int jhi = cm >> 1;
            wv[i][0] = vd * 64 + ((kbp * 4 + qa) ^ vd7) * 8 + jhi * 4;
            wv[i][1] = vd * 64 + ((kbp * 4 + qb) ^ vd7) * 8 + jhi * 4;
        }
    }

    const int np = (b48 >= 32) ? 2 : 1;

    for (int part = 0; part < np; ++part) {
        const int qt = (part == 0) ? (63 - b48) : (b48 - 32);
        const int q0 = qt * 64;
        const int nk = qt + 1;

        // Q fragment (B-operand: B[n=l16][k=quad*8+j])
        bh8 qa0, qa1;
        {
            const u16* qrow = Qh + ((size_t)h * SEQ + q0 + w * 16 + l16) * DK;
            qa0 = *(const bh8*)(qrow + quad * 8);
            qa1 = *(const bh8*)(qrow + 32 + quad * 8);
        }

        f4 o[4];               // O^T: lane l16 = q-row, row quad*4+r = dim
        float lsum = 0.f;
#pragma unroll
        for (int j = 0; j < 4; ++j) { f4 z = {0.f,0.f,0.f,0.f}; o[j] = z; }

        // ---- prologue: stage tile 0 into buffer 0 ----
        __syncthreads();       // protect buffers from previous part's readers
#pragma unroll
        for (int i = 0; i < 2; ++i)
            __builtin_amdgcn_global_load_lds(
                (const __attribute__((address_space(1))) unsigned int*)(Kbase + koff[i]),
                (__attribute__((address_space(3))) unsigned int*)&Ks[0][(w * 128 + i * 64) * 8],
                16, 0, 0);
        {
            uint4 v0 = *(const uint4*)&Vbase[(size_t)vd * SEQ + vs0];
            uint4 v1 = *(const uint4*)&Vbase[(size_t)vd * SEQ + vs0 + 8];
            uint2 c;
            c.x = v0.x; c.y = v0.y; *(uint2*)&Vs[0][wv[0][0]] = c;
            c.x = v0.z; c.y = v0.w; *(uint2*)&Vs[0][wv[0][1]] = c;
            c.x = v1.x; c.y = v1.y; *(uint2*)&Vs[0][wv[1][0]] = c;
            c.x = v1.z; c.y = v1.w; *(uint2*)&Vs[0][wv[1][1]] = c;
        }
        __syncthreads();       // tile 0 resident (drains gld vmcnt + ds writes)

        int b = 0;
        uint4 v0n, v1n;
        for (int kt = 0; kt < nk; ++kt) {
            const bool have_next = (kt + 1 < nk);

            if (have_next) {   // issue next-tile loads early
                const int kn = (kt + 1) * 64;
#pragma unroll
                for (int i = 0; i < 2; ++i)
                    __builtin_amdgcn_global_load_lds(
                        (const __attribute__((address_space(1))) unsigned int*)(Kbase + (size_t)kn * DK + koff[i]),
                        (__attribute__((address_space(3))) unsigned int*)&Ks[b ^ 1][(w * 128 + i * 64) * 8],
                        16, 0, 0);
                v0n = *(const uint4*)&Vbase[(size_t)vd * SEQ + kn + vs0];
                v1n = *(const uint4*)&Vbase[(size_t)vd * SEQ + kn + vs0 + 8];
            }

            // ---- S^T = K*Q^T: per lane, col=q-row l16, row=key quad*4+r ----
            float sv[4][4];
            __builtin_amdgcn_s_setprio(1);
#pragma unroll
            for (int kb = 0; kb < 4; ++kb) {
                const int rb = (kb * 16 + l16) * 64;
                bh8 kf0 = *(const bh8*)&Ks[b][rb + sA];
                bh8 kf1 = *(const bh8*)&Ks[b][rb + sB];
                f4 a = {0.f,0.f,0.f,0.f};
                a = __builtin_amdgcn_mfma_f32_16x16x32_bf16(kf0, qa0, a, 0, 0, 0);  // A=K, B=Q
                a = __builtin_amdgcn_mfma_f32_16x16x32_bf16(kf1, qa1, a, 0, 0, 0);
#pragma unroll
                for (int r = 0; r < 4; ++r) sv[kb][r] = a[r];
            }
            __builtin_amdgcn_s_setprio(0);
            // diagonal masking: key = kb*16+quad*4+r, q-row = w*16+l16
            if (kt == qt) {
#pragma unroll
                for (int kb = 0; kb < 4; ++kb)
#pragma unroll
                    for (int r = 0; r < 4; ++r)
                        if (kb * 16 + quad * 4 + r > w * 16 + l16) sv[kb][r] = -1.0e30f;
            }

            // ---- p = 2^sv (Q pre-scaled) ----
            float p[4][4];
#pragma unroll
            for (int kb = 0; kb < 4; ++kb) {
                p[kb][0] = exp2f(sv[kb][0]); p[kb][1] = exp2f(sv[kb][1]);
                p[kb][2] = exp2f(sv[kb][2]); p[kb][3] = exp2f(sv[kb][3]);
                lsum += (p[kb][0] + p[kb][1]) + (p[kb][2] + p[kb][3]);
            }

            // ---- PV: 8x mfma_16x16x32, permuted b128 V fragments ----
            __builtin_amdgcn_s_setprio(1);
#pragma unroll
            for (int kbp = 0; kbp < 2; ++kbp) {
                union { unsigned u[4]; bh8 v; } pc;
                pc.u[0] = pk2(p[2*kbp][0],     p[2*kbp][1]);
                pc.u[1] = pk2(p[2*kbp][2],     p[2*kbp][3]);
                pc.u[2] = pk2(p[2*kbp + 1][0], p[2*kbp + 1][1]);
                pc.u[3] = pk2(p[2*kbp + 1][2], p[2*kbp + 1][3]);
                const bh8 pb = pc.v;
                const int sc = kbp ? sB : sA;
#pragma unroll
                for (int jd = 0; jd < 4; ++jd) {
                    bh8 va = *(const bh8*)&Vs[b][(jd * 16 + l16) * 64 + sc];
                    o[jd] = __builtin_amdgcn_mfma_f32_16x16x32_bf16(va, pb, o[jd], 0, 0, 0);
                }
            }
            __builtin_amdgcn_s_setprio(0);

            if (have_next) {   // write next V tile, flip buffers
                uint2 c;
                c.x = v0n.x; c.y = v0n.y; *(uint2*)&Vs[b ^ 1][wv[0][0]] = c;
                c.x = v0n.z; c.y = v0n.w; *(uint2*)&Vs[b ^ 1][wv[0][1]] = c;
                c.x = v1n.x; c.y = v1n.y; *(uint2*)&Vs[b ^ 1][wv[1][0]] = c;
                c.x = v1n.z; c.y = v1n.w; *(uint2*)&Vs[b ^ 1][wv[1][1]] = c;
                __syncthreads();   // drains K gld vmcnt + V ds writes
                b ^= 1;
            }
        }

        // ---- epilogue: reduce l across quads (rows live in l16), store ----
        lsum += __shfl_xor(lsum, 16);
        lsum += __shfl_xor(lsum, 32);
        const float linv = 1.f / lsum;
        const size_t rowbase = (size_t)(q0 + w * 16 + l16) * DMODEL + h * DK;
#pragma unroll
        for (int jd = 0; jd < 4; ++jd) {
            unsigned lo = (unsigned)f2b(o[jd][0] * linv) | ((unsigned)f2b(o[jd][1] * linv) << 16);
            unsigned hi = (unsigned)f2b(o[jd][2] * linv) | ((unsigned)f2b(o[jd][3] * linv) << 16);
            uint2 pkd; pkd.x = lo; pkd.y = hi;
            *(uint2*)&ctx[rowbase + jd * 16 + quad * 4] = pkd;   // O[row][d..d+3]
        }
    }
}

// ---------------------------------------------------------------------------
extern "C" void kernel_launch(void* const* d_in, const int* in_sizes, int n_in,
                              void* d_out, int out_size, void* d_ws, size_t ws_size,
                              hipStream_t stream)
{
    const float* x  = (const float*)d_in[0];
    const float* wq = (const float*)d_in[1];
    const float* wk = (const float*)d_in[2];
    const float* wv = (const float*)d_in[3];
    const float* wo = (const float*)d_in[4];
    float* out = (float*)d_out;

    char* ws = (char*)d_ws;
    const size_t MB = 1u << 20;
    u16* xb   = (u16*)(ws);              // 8 MB  [4096][1024] bf16
    u16* wqkv = (u16*)(ws + 8  * MB);    // 6 MB  [3072][1024] bf16 (wq|wk|wv)
    u16* wob  = (u16*)(ws + 14 * MB);    // 2 MB  (contiguous after wqkv)
    u16* Qh   = (u16*)(ws + 16 * MB);    // 8 MB  [h][s][64]  (pre-scaled by 0.125*log2e)
    u16* Kh   = (u16*)(ws + 24 * MB);    // 8 MB
    u16* Vtb  = (u16*)(ws + 32 * MB);    // 8 MB  [h][64][s]
    u16* ctxb = (u16*)(ws + 40 * MB);    // 8 MB  [s][1024]

    const int NCVT = SEQ * DMODEL / 8 + 4 * (DMODEL * DMODEL / 8);   // 1048576
    cvt_all_kernel<<<NCVT / 256, 256, 0, stream>>>(x, wq, wk, wv, wo, xb, wqkv);

    dim3 gqkv(3 * DMODEL / 128, SEQ / 128);   // (24, 32) = 768 blocks
    gemm_bt<2><<<gqkv, 256, 0, stream>>>(xb, wqkv, nullptr, Qh, Kh, Vtb,
                                         SEQ, 3 * DMODEL, DMODEL);

    attn_mfma_kernel<<<dim3(48, NHEADS), 256, 0, stream>>>(Qh, Kh, Vtb, ctxb);

    dim3 go(DMODEL / 64, SEQ / 128);          // (16, 32) = 512 blocks
    gemm_bt<0><<<go, 256, 0, stream>>>(ctxb, wob, out, nullptr, nullptr, nullptr,
                                       SEQ, DMODEL, DMODEL);
}

// Round 3
// 225.449 us; speedup vs baseline: 1.0949x; 1.0378x over previous
//
#include <hip/hip_runtime.h>
#include <math.h>

#define SEQ    4096
#define DMODEL 1024
#define NHEADS 16
#define DK     64

typedef unsigned short u16;
typedef short bh8 __attribute__((ext_vector_type(8)));   // 8 x bf16 (4 VGPRs)
typedef float f4  __attribute__((ext_vector_type(4)));   // 4 x fp32 acc

__device__ __forceinline__ u16 f2b(float f) {            // RNE
    union { float f; unsigned u; } v; v.f = f;
    unsigned u = v.u;
    return (u16)((u + 0x7FFFu + ((u >> 16) & 1u)) >> 16);
}
__device__ __forceinline__ unsigned pk2(float a, float b) {  // trunc pack 2xbf16
    union { float f; unsigned u; } ua, ub; ua.f = a; ub.f = b;
    return (ua.u >> 16) | (ub.u & 0xFFFF0000u);
}

// ---------------------------------------------------------------------------
// Merged fp32 -> bf16 convert for x and all 4 weights (one launch).
// ---------------------------------------------------------------------------
__global__ void cvt_all_kernel(const float* __restrict__ x,
                               const float* __restrict__ wq, const float* __restrict__ wk,
                               const float* __restrict__ wv, const float* __restrict__ wo,
                               u16* __restrict__ xb, u16* __restrict__ wb)
{
    const int NX = SEQ * DMODEL / 8;        // 524288 chunks of 8
    const int NW = DMODEL * DMODEL / 8;     // 131072
    int i = blockIdx.x * blockDim.x + threadIdx.x;
    if (i >= NX + 4 * NW) return;
    const float* src; u16* dst; int j;
    if (i < NX) { src = x; dst = xb; j = i; }
    else {
        int k = i - NX;
        int wsel = k >> 17;                 // NW = 2^17
        j = k & (NW - 1);
        src = (wsel == 0) ? wq : (wsel == 1) ? wk : (wsel == 2) ? wv : wo;
        dst = wb + (size_t)wsel * DMODEL * DMODEL;
    }
    const float4* p = (const float4*)src + (size_t)j * 2;
    float4 a = p[0], b = p[1];
    __align__(16) u16 r[8] = { f2b(a.x), f2b(a.y), f2b(a.z), f2b(a.w),
                               f2b(b.x), f2b(b.y), f2b(b.z), f2b(b.w) };
    *(uint4*)(dst + (size_t)j * 8) = *(const uint4*)r;
}

// ---------------------------------------------------------------------------
// bf16 MFMA GEMM (bt-form), BK=32, 4 waves.
// MODE 0: 128x64 tile, fp32 out.  MODE 2: 128x128, fused QKV epilogue
// (Q: RoPE * 0.125*log2e pre-scale -> [h][s][64]; K: RoPE -> [h][s][64];
//  V: transposed -> [h][64][s]).
// ---------------------------------------------------------------------------
template<int MODE>
__global__ __launch_bounds__(256) void gemm_bt(
    const u16* __restrict__ A, const u16* __restrict__ B,
    void* __restrict__ out, u16* __restrict__ Qh, u16* __restrict__ Kh,
    u16* __restrict__ Vt, int M, int N, int K)
{
    constexpr int BN = (MODE == 0) ? 64 : 128;
    constexpr int NJ = BN / 32;             // j-tiles per wave (2 or 4)

    __shared__ __align__(16) u16 As[128 * 32];
    __shared__ __align__(16) u16 Bs[BN * 32];

    const int t    = threadIdx.x;
    const int w    = t >> 6, lane = t & 63;
    const int quad = lane >> 4, l16 = lane & 15;
    const int wm   = w >> 1,  wn  = w & 1;
    const int m0   = blockIdx.y * 128, n0 = blockIdx.x * BN;
    const int lr   = lane >> 2;             // 0..15
    const int lc   = (lane & 3) * 8;        // 0,8,16,24

    f4 acc[4][NJ];
#pragma unroll
    for (int i = 0; i < 4; ++i)
#pragma unroll
        for (int j = 0; j < NJ; ++j) { f4 z = {0.f,0.f,0.f,0.f}; acc[i][j] = z; }

    const int c0 = 2 * w, c1 = 2 * w + 1;

    for (int k0 = 0; k0 < K; k0 += 32) {
        __builtin_amdgcn_global_load_lds(
            (const __attribute__((address_space(1))) unsigned int*)(A + (size_t)(m0 + c0*16 + lr)*K + k0 + lc),
            (__attribute__((address_space(3))) unsigned int*)(As + c0*512), 16, 0, 0);
        __builtin_amdgcn_global_load_lds(
            (const __attribute__((address_space(1))) unsigned int*)(A + (size_t)(m0 + c1*16 + lr)*K + k0 + lc),
            (__attribute__((address_space(3))) unsigned int*)(As + c1*512), 16, 0, 0);
        if (MODE == 0) {
            __builtin_amdgcn_global_load_lds(
                (const __attribute__((address_space(1))) unsigned int*)(B + (size_t)(n0 + w*16 + lr)*K + k0 + lc),
                (__attribute__((address_space(3))) unsigned int*)(Bs + w*512), 16, 0, 0);
        } else {
            __builtin_amdgcn_global_load_lds(
                (const __attribute__((address_space(1))) unsigned int*)(B + (size_t)(n0 + c0*16 + lr)*K + k0 + lc),
                (__attribute__((address_space(3))) unsigned int*)(Bs + c0*512), 16, 0, 0);
            __builtin_amdgcn_global_load_lds(
                (const __attribute__((address_space(1))) unsigned int*)(B + (size_t)(n0 + c1*16 + lr)*K + k0 + lc),
                (__attribute__((address_space(3))) unsigned int*)(Bs + c1*512), 16, 0, 0);
        }
        __syncthreads();

        bh8 af[4], bf_[NJ];
#pragma unroll
        for (int i = 0; i < 4; ++i)
            af[i] = *(const bh8*)&As[(wm*64 + i*16 + l16)*32 + quad*8];
#pragma unroll
        for (int j = 0; j < NJ; ++j)
            bf_[j] = *(const bh8*)&Bs[(wn*(BN/2) + j*16 + l16)*32 + quad*8];
#pragma unroll
        for (int i = 0; i < 4; ++i)
#pragma unroll
            for (int j = 0; j < NJ; ++j)
                acc[i][j] = __builtin_amdgcn_mfma_f32_16x16x32_bf16(af[i], bf_[j], acc[i][j], 0, 0, 0);
        __syncthreads();
    }

    if (MODE == 0) {
#pragma unroll
        for (int i = 0; i < 4; ++i) {
            const int row = m0 + wm*64 + i*16 + quad*4;
#pragma unroll
            for (int j = 0; j < NJ; ++j) {
                const int col = n0 + wn*(BN/2) + j*16 + l16;
#pragma unroll
                for (int r = 0; r < 4; ++r)
                    ((float*)out)[(size_t)(row + r) * N + col] = acc[i][j][r];
            }
        }
    } else {
        const int sect  = n0 >> 10;                   // 0=Q,1=K,2=V (block-uniform)
        const int cbase = (n0 & 1023) + wn * 64;      // 64-aligned head base
        const int hh    = cbase >> 6;                 // head (wave-uniform)
        if (sect < 2) {
            u16* dst = (sect == 0) ? Qh : Kh;
            const float qscl = (sect == 0) ? 0.18033688011112042f : 1.0f; // 0.125*log2(e)
#pragma unroll
            for (int j = 0; j < NJ; ++j) {
                const int d = j * 16 + l16;           // 0..63 within head
                const float invf2 = exp2f((float)(d & ~1) * (-13.287712379549449f / 64.0f))
                                    * 0.15915494309189535f;
#pragma unroll
                for (int i = 0; i < 4; ++i) {
                    const int srow0 = m0 + wm*64 + i*16 + quad*4;
#pragma unroll
                    for (int r = 0; r < 4; ++r) {
                        float own = acc[i][j][r];
                        float oth = __shfl_xor(own, 1);      // rope pair partner
                        float rev = (float)(srow0 + r) * invf2;
                        rev -= floorf(rev);                   // v_sin input: revolutions
                        float sn = __builtin_amdgcn_sinf(rev);
                        float cs = __builtin_amdgcn_cosf(rev);
                        float xe = (l16 & 1) ? oth : own;
                        float xo = (l16 & 1) ? own : oth;
                        float val = (l16 & 1) ? (sn * xe + cs * xo)
                                              : (cs * xe - sn * xo);
                        dst[((size_t)hh * SEQ + srow0 + r) * DK + d] = f2b(val * qscl);
                    }
                }
            }
        } else {
#pragma unroll
            for (int j = 0; j < NJ; ++j) {
                const int d = j * 16 + l16;
#pragma unroll
                for (int i = 0; i < 4; ++i) {
                    const int srow0 = m0 + wm*64 + i*16 + quad*4;
                    __align__(8) u16 pk[4];
#pragma unroll
                    for (int r = 0; r < 4; ++r) pk[r] = f2b(acc[i][j][r]);
                    *(unsigned long long*)&Vt[((size_t)hh * DK + d) * SEQ + srow0] =
                        *(const unsigned long long*)pk;
                }
            }
        }
    }
}

// ---------------------------------------------------------------------------
// MFMA flash attention, register-resident P.
// R3: occupancy + balance restructure (inner math identical to R2).
//  * Grid (32, NHEADS), 512-thread blocks (8 waves). Each block runs the
//    constant-work pair qt = bx then qt = 63-bx (65 steps total, ALL blocks
//    equal -> zero imbalance; 2 blocks/CU, 16 waves/CU = 50% occupancy,
//    up from 3 imbalanced 4-wave blocks at 21%).
//  * Within a step the 8 waves split the 64 keys: half hh = w>>2 owns
//    kb in {2hh, 2hh+1} (4 QK + 4 PV mfmas, half the exp2/pack per wave).
//    Per-block-step totals (MFMA, LDS traffic) unchanged. The P<->V key
//    permutation is invariant under kbp = hh.
//  * O/l partials merged across halves once per q-tile via stride-20 LDS
//    scratch (softmax is max-free -> additive merge). ~2% overhead.
//  * Staging per thread: 1x16B global_load_lds (K, swizzle in source addr),
//    1 uint4 + 2 permuted uint2 ds_writes (V). Same conflict-free formulas.
// ---------------------------------------------------------------------------
__global__ __launch_bounds__(512) void attn_mfma_kernel(
    const u16* __restrict__ Qh, const u16* __restrict__ Kh,
    const u16* __restrict__ Vt, u16* __restrict__ ctx)
{
    __shared__ __align__(16) u16 Ks[2][64 * 64];   // [key][d]   (swizzled slots)
    __shared__ __align__(16) u16 Vs[2][64 * 64];   // [d][key']  (permuted+swizzled)

    const int h    = blockIdx.y;
    const int bx   = blockIdx.x;                   // 0..31
    const int t    = threadIdx.x;                  // 0..511
    const int w    = t >> 6, lane = t & 63;
    const int wl   = w & 3, hh = w >> 2;           // q-slice, key-half
    const int quad = lane >> 4, l16 = lane & 15;

    const u16* Kbase = Kh + (size_t)h * SEQ * DK;
    const u16* Vbase = Vt + (size_t)h * DK * SEQ;

    // fragment-read swizzled column offsets (u16 units): logical 16B slot L
    // at row r lives at physical slot L ^ (r&7); fragment rows have low3 = l16&7.
    const int sA = ((quad       ^ (l16 & 7)) * 8);   // slots 0..3
    const int sB = (((4 + quad) ^ (l16 & 7)) * 8);   // slots 4..7

    // K staging (global_load_lds): 1 x 16B/thread. Dest 16B-slot = w*64+lane
    // (linear); row r = slot>>3 = w*8 + (lane>>3), s = slot&7;
    // source col = (s ^ (r&7))*8.  (w*8 ≡ 0 mod 8 so r&7 = lane>>3.)
    int koff;
    {
        const int r7 = lane >> 3;
        const int s  = lane & 7;
        koff = (w * 8 + r7) * DK + ((s ^ r7) * 8);
    }

    // V staging (reg + ds_write): thread t owns row d = t>>3, 16B source
    // group c2 = t&7 (keys c2*8..c2*8+7). The uint4 splits into two 4-key
    // chunks written at permuted kappas (kappa(key): kbp=key>>5,
    // jhi=(key>>4)&1, q=(key>>2)&3, jl=key&3 -> kbp*32 + q*8 + jhi*4 + jl),
    // slot swizzle ^= d&7.
    const int vd  = t >> 3;                 // 0..63
    const int vs0 = (t & 7) * 8;            // source col (u16)
    int wv0, wv1;
    {
        const int vd7 = vd & 7;
        const int c2  = t & 7;
        const int kbp = c2 >> 2, cm = c2 & 3;
        const int qa  = (2 * cm) & 3;
        const int qb  = (2 * cm + 1) & 3;
        const int jhi = cm >> 1;
        wv0 = vd * 64 + ((kbp * 4 + qa) ^ vd7) * 8 + jhi * 4;
        wv1 = vd * 64 + ((kbp * 4 + qb) ^ vd7) * 8 + jhi * 4;
    }

    for (int part = 0; part < 2; ++part) {
        const int qt = part ? (63 - bx) : bx;
        const int q0 = qt * 64;
        const int nk = qt + 1;

        // Q fragment (B-operand: B[n=l16][k=quad*8+j]) — same for both halves
        bh8 qa0, qa1;
        {
            const u16* qrow = Qh + ((size_t)h * SEQ + q0 + wl * 16 + l16) * DK;
            qa0 = *(const bh8*)(qrow + quad * 8);
            qa1 = *(const bh8*)(qrow + 32 + quad * 8);
        }

        f4 o[4];               // O^T partial (this key-half): q=l16, d=jd*16+quad*4+r
        float lsum = 0.f;
#pragma unroll
        for (int j = 0; j < 4; ++j) { f4 z = {0.f,0.f,0.f,0.f}; o[j] = z; }

        // ---- prologue: stage tile 0 into buffer 0 ----
        __syncthreads();       // protect LDS from previous part's epilogue
        __builtin_amdgcn_global_load_lds(
            (const __attribute__((address_space(1))) unsigned int*)(Kbase + koff),
            (__attribute__((address_space(3))) unsigned int*)&Ks[0][w * 512],
            16, 0, 0);
        {
            uint4 v0 = *(const uint4*)&Vbase[(size_t)vd * SEQ + vs0];
            uint2 c;
            c.x = v0.x; c.y = v0.y; *(uint2*)&Vs[0][wv0] = c;
            c.x = v0.z; c.y = v0.w; *(uint2*)&Vs[0][wv1] = c;
        }
        __syncthreads();       // tile 0 resident (drains gld vmcnt + ds writes)

        int b = 0;
        uint4 v0n;
        for (int kt = 0; kt < nk; ++kt) {
            const bool have_next = (kt + 1 < nk);

            if (have_next) {   // issue next-tile loads early
                const int kn = (kt + 1) * 64;
                __builtin_amdgcn_global_load_lds(
                    (const __attribute__((address_space(1))) unsigned int*)(Kbase + (size_t)kn * DK + koff),
                    (__attribute__((address_space(3))) unsigned int*)&Ks[b ^ 1][w * 512],
                    16, 0, 0);
                v0n = *(const uint4*)&Vbase[(size_t)vd * SEQ + kn + vs0];
            }

            // ---- S^T = K*Q^T for this wave's key-half ----
            float sv[2][4];
            __builtin_amdgcn_s_setprio(1);
#pragma unroll
            for (int kk = 0; kk < 2; ++kk) {
                const int kb = hh * 2 + kk;
                const int rb = (kb * 16 + l16) * 64;
                bh8 kf0 = *(const bh8*)&Ks[b][rb + sA];
                bh8 kf1 = *(const bh8*)&Ks[b][rb + sB];
                f4 a = {0.f,0.f,0.f,0.f};
                a = __builtin_amdgcn_mfma_f32_16x16x32_bf16(kf0, qa0, a, 0, 0, 0);  // A=K, B=Q
                a = __builtin_amdgcn_mfma_f32_16x16x32_bf16(kf1, qa1, a, 0, 0, 0);
#pragma unroll
                for (int r = 0; r < 4; ++r) sv[kk][r] = a[r];
            }
            __builtin_amdgcn_s_setprio(0);
            // diagonal masking: key = (hh*2+kk)*16+quad*4+r, q-row = wl*16+l16
            if (kt == qt) {
#pragma unroll
                for (int kk = 0; kk < 2; ++kk)
#pragma unroll
                    for (int r = 0; r < 4; ++r)
                        if ((hh * 2 + kk) * 16 + quad * 4 + r > wl * 16 + l16)
                            sv[kk][r] = -1.0e30f;
            }

            // ---- p = 2^sv (Q pre-scaled) ----
            float p[2][4];
#pragma unroll
            for (int kk = 0; kk < 2; ++kk) {
                p[kk][0] = exp2f(sv[kk][0]); p[kk][1] = exp2f(sv[kk][1]);
                p[kk][2] = exp2f(sv[kk][2]); p[kk][3] = exp2f(sv[kk][3]);
                lsum += (p[kk][0] + p[kk][1]) + (p[kk][2] + p[kk][3]);
            }

            // ---- PV: 4x mfma_16x16x32 over this half's 32 keys (kbp = hh) ----
            {
                union { unsigned u[4]; bh8 v; } pc;
                pc.u[0] = pk2(p[0][0], p[0][1]);
                pc.u[1] = pk2(p[0][2], p[0][3]);
                pc.u[2] = pk2(p[1][0], p[1][1]);
                pc.u[3] = pk2(p[1][2], p[1][3]);
                const bh8 pb = pc.v;
                const int sc = hh ? sB : sA;
                __builtin_amdgcn_s_setprio(1);
#pragma unroll
                for (int jd = 0; jd < 4; ++jd) {
                    bh8 va = *(const bh8*)&Vs[b][(jd * 16 + l16) * 64 + sc];
                    o[jd] = __builtin_amdgcn_mfma_f32_16x16x32_bf16(va, pb, o[jd], 0, 0, 0);
                }
                __builtin_amdgcn_s_setprio(0);
            }

            if (have_next) {   // write next V tile, flip buffers
                uint2 c;
                c.x = v0n.x; c.y = v0n.y; *(uint2*)&Vs[b ^ 1][wv0] = c;
                c.x = v0n.z; c.y = v0n.w; *(uint2*)&Vs[b ^ 1][wv1] = c;
                __syncthreads();   // drains K gld vmcnt + V ds writes
                b ^= 1;
            }
        }

        // ---- epilogue: quad-reduce l, merge halves via LDS, store ----
        lsum += __shfl_xor(lsum, 16);
        lsum += __shfl_xor(lsum, 32);
        __syncthreads();           // all LDS K/V reads of this part done
        // scratch record: 20 floats/lane (16 O + 1 l), 16B-aligned, stride-20
        // banks conflict-free. Waves 4..7 write; 0..3 read the partner record.
        float* scr = ((w & 2) ? (float*)Vs : (float*)Ks)
                     + ((w & 1) * 64 + lane) * 20;
        if (hh) {
#pragma unroll
            for (int jd = 0; jd < 4; ++jd) *(f4*)(scr + jd * 4) = o[jd];
            scr[16] = lsum;
        }
        __syncthreads();
        if (!hh) {
#pragma unroll
            for (int jd = 0; jd < 4; ++jd) {
                f4 po = *(const f4*)(scr + jd * 4);
#pragma unroll
                for (int r = 0; r < 4; ++r) o[jd][r] += po[r];
            }
            lsum += scr[16];
            const float linv = 1.f / lsum;
            const size_t rowbase = (size_t)(q0 + wl * 16 + l16) * DMODEL + h * DK;
#pragma unroll
            for (int jd = 0; jd < 4; ++jd) {
                unsigned lo = (unsigned)f2b(o[jd][0] * linv) | ((unsigned)f2b(o[jd][1] * linv) << 16);
                unsigned hi = (unsigned)f2b(o[jd][2] * linv) | ((unsigned)f2b(o[jd][3] * linv) << 16);
                uint2 pkd; pkd.x = lo; pkd.y = hi;
                *(uint2*)&ctx[rowbase + jd * 16 + quad * 4] = pkd;   // O[row][d..d+3]
            }
        }
    }
}

// ---------------------------------------------------------------------------
extern "C" void kernel_launch(void* const* d_in, const int* in_sizes, int n_in,
                              void* d_out, int out_size, void* d_ws, size_t ws_size,
                              hipStream_t stream)
{
    const float* x  = (const float*)d_in[0];
    const float* wq = (const float*)d_in[1];
    const float* wk = (const float*)d_in[2];
    const float* wv = (const float*)d_in[3];
    const float* wo = (const float*)d_in[4];
    float* out = (float*)d_out;

    char* ws = (char*)d_ws;
    const size_t MB = 1u << 20;
    u16* xb   = (u16*)(ws);              // 8 MB  [4096][1024] bf16
    u16* wqkv = (u16*)(ws + 8  * MB);    // 6 MB  [3072][1024] bf16 (wq|wk|wv)
    u16* wob  = (u16*)(ws + 14 * MB);    // 2 MB  (contiguous after wqkv)
    u16* Qh   = (u16*)(ws + 16 * MB);    // 8 MB  [h][s][64]  (pre-scaled by 0.125*log2e)
    u16* Kh   = (u16*)(ws + 24 * MB);    // 8 MB
    u16* Vtb  = (u16*)(ws + 32 * MB);    // 8 MB  [h][64][s]
    u16* ctxb = (u16*)(ws + 40 * MB);    // 8 MB  [s][1024]

    const int NCVT = SEQ * DMODEL / 8 + 4 * (DMODEL * DMODEL / 8);   // 1048576
    cvt_all_kernel<<<NCVT / 256, 256, 0, stream>>>(x, wq, wk, wv, wo, xb, wqkv);

    dim3 gqkv(3 * DMODEL / 128, SEQ / 128);   // (24, 32) = 768 blocks
    gemm_bt<2><<<gqkv, 256, 0, stream>>>(xb, wqkv, nullptr, Qh, Kh, Vtb,
                                         SEQ, 3 * DMODEL, DMODEL);

    attn_mfma_kernel<<<dim3(32, NHEADS), 512, 0, stream>>>(Qh, Kh, Vtb, ctxb);

    dim3 go(DMODEL / 64, SEQ / 128);          // (16, 32) = 512 blocks
    gemm_bt<0><<<go, 256, 0, stream>>>(ctxb, wob, out, nullptr, nullptr, nullptr,
                                       SEQ, DMODEL, DMODEL);
}